// Round 11
// baseline (290.807 us; speedup 1.0000x reference)
//
#include <hip/hip_runtime.h>
#include <math.h>

// Problem constants
#define Bb   256
#define Nn   16384
#define Dd   512
#define NNZn 540672
#define DFf  2048
#define SLOT 64    // packed bucket width (max row count ~58 for Binom(540672,1/16384))

// k_prep roles: weight cvt (W_v,W_o,W_f1,W_f2,W_in) | x0 transpose | bucketing.
// W_out cvt rides in gemm_v / gemm_at (128-block launches = half machine idle).
// Scatter blocks interleaved 1-in-2 over the leading dispatch range (no tail).
#define CVT_BLKS 2688   // 2,752,512 vec4 / 1024
#define TR_BLKS  1024
#define BK_BLKS  2112   // 540672 / 256 exactly
#define PREP_BLKS (CVT_BLKS + TR_BLKS + BK_BLKS)   // 5824

// cvt segment boundaries (vec4 units)
#define C1 65536      // W_v
#define C2 131072     // W_o
#define C3 393216     // W_f1
#define C4 655360     // W_f2
#define C5 2752512    // W_in end
#define WOUT_VEC4 2097152   // W_out: 2,097,152 vec4 total (split across 2 riders)

typedef __bf16 bf16;
typedef __bf16 bf16x4 __attribute__((ext_vector_type(4)));
typedef __bf16 bf16x8 __attribute__((ext_vector_type(8)));
typedef float  f32x4  __attribute__((ext_vector_type(4)));

// ---------------------------------------------------------------- async G->LDS
__device__ __forceinline__ void gload16(const void* g, void* l) {
  __builtin_amdgcn_global_load_lds(
      (const __attribute__((address_space(1))) unsigned int*)g,
      (__attribute__((address_space(3))) unsigned int*)l, 16, 0, 0);
}

// Counted-vmcnt barrier (T4): drain all but NK outstanding VMEM ops, then
// raw s_barrier.  NK>0 keeps the freshly issued tile-(t+2) stage in flight.
template <int NK>
__device__ __forceinline__ void bar_keep() {
  asm volatile("s_waitcnt vmcnt(%0) lgkmcnt(0)" :: "n"(NK) : "memory");
  __builtin_amdgcn_s_barrier();
}

__device__ __forceinline__ float f16_of(unsigned e) {
  unsigned short us = (unsigned short)(e & 0xffff);
  _Float16 h;
  __builtin_memcpy(&h, &us, 2);
  return (float)h;
}

// ---- merged prep: weight cvt (x5) | x0 transpose | nnz bucketing (packed).
// Bucketing blocks are 1-in-2 over the first 4224 dispatch slots so their
// scatter/atomic latency overlaps streaming BW; streaming-only tail is fine.
// Also zeroes d_loss (k_prep is always the first kernel).
__global__ __launch_bounds__(256) void k_prep(
    const float* __restrict__ w_v, const float* __restrict__ w_o,
    const float* __restrict__ w_f1, const float* __restrict__ w_f2,
    const float* __restrict__ w_in,
    bf16* __restrict__ o_v, bf16* __restrict__ o_o,
    bf16* __restrict__ o_f1, bf16* __restrict__ o_f2,
    bf16* __restrict__ o_in,
    const float* __restrict__ x0, bf16* __restrict__ x0T,
    const int* __restrict__ rows, const int* __restrict__ cols,
    const float* __restrict__ vals,
    int* __restrict__ counts, unsigned* __restrict__ ents,
    float* __restrict__ d_loss) {
  __shared__ float tile[64][65];
  int blk = blockIdx.x;
  if (blk == 0 && threadIdx.x == 0) *d_loss = 0.f;
  int q = blk >> 1;
  if (!(blk & 1) && q < BK_BLKS) {
    // ---- bucketing role (2112 virtual blocks, 1-in-2 over leading range)
    int i = q * 256 + threadIdx.x;  // exact: 540672
    int r = rows[i];
    int p = atomicAdd(&counts[r], 1);
    if (p < SLOT) {
      _Float16 hv = (_Float16)vals[i];
      unsigned short us;
      __builtin_memcpy(&us, &hv, 2);
      ents[(size_t)r * SLOT + p] = ((unsigned)cols[i] << 16) | (unsigned)us;
    }
  } else {
    int sB = (blk + 1) >> 1; if (sB > BK_BLKS) sB = BK_BLKS;
    int o = blk - sB;       // streaming index 0..3711
    if (o < CVT_BLKS) {
      int v0i = o * 1024 + threadIdx.x;
#pragma unroll
      for (int j = 0; j < 4; j++) {
        int v = v0i + j * 256;
        const float* s; bf16* d; int base;
        if (v < C2)      { if (v < C1) { s = w_v;  d = o_v;  base = 0;  }
                           else        { s = w_o;  d = o_o;  base = C1; } }
        else if (v < C4) { if (v < C3) { s = w_f1; d = o_f1; base = C2; }
                           else        { s = w_f2; d = o_f2; base = C3; } }
        else             { s = w_in; d = o_in; base = C4; }
        int idx = (v - base) * 4;
        float4 x = *(const float4*)(s + idx);
        bf16x4 ob;
        ob[0] = (bf16)x.x; ob[1] = (bf16)x.y; ob[2] = (bf16)x.z; ob[3] = (bf16)x.w;
        *(bf16x4*)(d + idx) = ob;
      }
    } else {
      int bx = o - CVT_BLKS;
      int n0 = (bx & 255) * 64, b0 = (bx >> 8) * 64;
      int tx = threadIdx.x & 63, ty = threadIdx.x >> 6;   // ty 0..3
#pragma unroll
      for (int i = 0; i < 16; i++) {
        int bl = ty * 16 + i;
        tile[bl][tx] = x0[(size_t)(b0 + bl) * Nn + n0 + tx];
      }
      __syncthreads();
#pragma unroll
      for (int i = 0; i < 16; i++) {
        int nl = ty * 16 + i;
        x0T[(size_t)(n0 + nl) * Bb + b0 + tx] = (bf16)tile[tx][nl];
      }
    }
  }
}

// ---- Lx[r][:] = sum_j val_j * x0T[col_j][:].  One WAVE per row; each lane
// holds 4 batch elems (bf16x4, 8 B) -> one gather instr = full 512 B row.
// Entries packed: col<<16 | fp16(val).  4-deep gather ILP.
__global__ __launch_bounds__(256) void k_lx(const bf16x4* __restrict__ x0T4,
                                            const int* __restrict__ counts,
                                            const unsigned* __restrict__ ents,
                                            bf16x4* __restrict__ Lx4) {
  int w = threadIdx.x >> 6, lane = threadIdx.x & 63;
  int r = blockIdx.x * 4 + w;
  __shared__ unsigned esm[4][64];
  int cnt = counts[r];
  if (cnt > SLOT) cnt = SLOT;
  const unsigned* ep = ents + (size_t)r * SLOT;
  float a0 = 0.f, a1 = 0.f, a2 = 0.f, a3 = 0.f;
  float b0 = 0.f, b1 = 0.f, b2 = 0.f, b3 = 0.f;
  float c0 = 0.f, c1 = 0.f, c2 = 0.f, c3 = 0.f;
  float d0 = 0.f, d1 = 0.f, d2 = 0.f, d3 = 0.f;
  for (int base = 0; base < cnt; base += 64) {
    int m = cnt - base; if (m > 64) m = 64;
    if (lane < m) esm[w][lane] = ep[base + lane];
    int i = 0;
    for (; i + 3 < m; i += 4) {
      unsigned e0 = esm[w][i],     e1 = esm[w][i + 1];
      unsigned e2 = esm[w][i + 2], e3 = esm[w][i + 3];
      bf16x4 xv0 = x0T4[(size_t)(e0 >> 16) * 64 + lane];
      bf16x4 xv1 = x0T4[(size_t)(e1 >> 16) * 64 + lane];
      bf16x4 xv2 = x0T4[(size_t)(e2 >> 16) * 64 + lane];
      bf16x4 xv3 = x0T4[(size_t)(e3 >> 16) * 64 + lane];
      float v0 = f16_of(e0), v1 = f16_of(e1), v2 = f16_of(e2), v3 = f16_of(e3);
      a0 += v0 * (float)xv0[0]; a1 += v0 * (float)xv0[1];
      a2 += v0 * (float)xv0[2]; a3 += v0 * (float)xv0[3];
      b0 += v1 * (float)xv1[0]; b1 += v1 * (float)xv1[1];
      b2 += v1 * (float)xv1[2]; b3 += v1 * (float)xv1[3];
      c0 += v2 * (float)xv2[0]; c1 += v2 * (float)xv2[1];
      c2 += v2 * (float)xv2[2]; c3 += v2 * (float)xv2[3];
      d0 += v3 * (float)xv3[0]; d1 += v3 * (float)xv3[1];
      d2 += v3 * (float)xv3[2]; d3 += v3 * (float)xv3[3];
    }
    for (; i < m; i++) {
      unsigned e0 = esm[w][i];
      bf16x4 xv0 = x0T4[(size_t)(e0 >> 16) * 64 + lane];
      float v0 = f16_of(e0);
      a0 += v0 * (float)xv0[0]; a1 += v0 * (float)xv0[1];
      a2 += v0 * (float)xv0[2]; a3 += v0 * (float)xv0[3];
    }
  }
  bf16x4 o;
  o[0] = (bf16)(a0 + b0 + c0 + d0); o[1] = (bf16)(a1 + b1 + c1 + d1);
  o[2] = (bf16)(a2 + b2 + c2 + d2); o[3] = (bf16)(a3 + b3 + c3 + d3);
  Lx4[(size_t)r * 64 + lane] = o;
}

// ---------------- x_t[b][n] = x0[b][n] - 0.5*t[b]*Lx[n][b]   (bf16, B-major)
__global__ __launch_bounds__(256) void k_combine(const float* __restrict__ x0,
                                                 const bf16* __restrict__ Lx,
                                                 const float* __restrict__ t,
                                                 bf16* __restrict__ xt) {
  __shared__ float lxs[64][65];
  int n0 = blockIdx.x * 64, b0 = blockIdx.y * 64;
  int tx = threadIdx.x & 63, ty = threadIdx.x >> 6;
#pragma unroll
  for (int i = 0; i < 16; i++) {
    int nl = ty * 16 + i;
    lxs[nl][tx] = (float)Lx[(size_t)(n0 + nl) * Bb + b0 + tx];
  }
  __syncthreads();
#pragma unroll
  for (int i = 0; i < 16; i++) {
    int bl = ty * 16 + i;
    int b  = b0 + bl;
    float tc = t[b] * 0.5f;   // T_MAX
    float v = x0[(size_t)b * Nn + n0 + tx] - tc * lxs[tx][bl];
    xt[(size_t)b * Nn + n0 + tx] = (bf16)v;
  }
}

// ------------------------------------------------------------- bf16 TN GEMM
// C[m][n] = sum_k A[m][k]*Bm[n][k].  All-bf16, all-gload16 staging.
// Depth-2 prefetch (T3/T4): triple-buffered LDS; stage(t+2) issued at iter t;
// counted-vmcnt barrier drains only tile t+1, keeps tile t+2 in flight.
//   MODE 0: store fp32 split-K partial at z*MN
//   MODE 1: direct bf16 store of acc+bias (ACT=1: exact gelu) -> C is bf16*
//   MODE 2: fused loss sum((C+bias-x0)^2) * 1/(B*N), one atomic per block
//           directly into the output scalar (zeroed by k_prep)
//   GY>0 : blocks with blockIdx.y >= GY are fp32->bf16 cvt rider blocks
//          (1024 vec4 each) converting cvs -> cvd starting at vec4 cvoff.
template <int BM, int BN, int MODE, int ACT = 0, int GY = 0>
__global__ __launch_bounds__(256) void gemm_tn(
    const bf16* __restrict__ A, const bf16* __restrict__ Bm,
    float* __restrict__ C, int N, int K, int kLen, int MN,
    const float* __restrict__ bias, const float* __restrict__ x0,
    float* __restrict__ lossOut,
    const float* __restrict__ cvs, bf16* __restrict__ cvd, int cvoff) {
  if constexpr (GY > 0) {
    if (blockIdx.y >= GY) {
      int cb = (blockIdx.y - GY) * gridDim.x + blockIdx.x;
      int v0 = cvoff + cb * 1024 + threadIdx.x;
#pragma unroll
      for (int j = 0; j < 4; j++) {
        int v = v0 + j * 256;
        float4 x = *(const float4*)(cvs + (size_t)v * 4);
        bf16x4 ob;
        ob[0] = (bf16)x.x; ob[1] = (bf16)x.y; ob[2] = (bf16)x.z; ob[3] = (bf16)x.w;
        *(bf16x4*)(cvd + (size_t)v * 4) = ob;
      }
      return;
    }
  }
  constexpr int WM = BM / 2, WN = BN / 2, FM = WM / 16, FN = WN / 16;
  constexpr int PASS = (BM + BN) / 64;  // 64B-chunk groups per stage (per wave)
  constexpr int KEEP = PASS;
  __shared__ __align__(16) bf16 As[3][BM * 32];
  __shared__ __align__(16) bf16 Bs[3][BN * 32];
  __shared__ float lred[4];
  const int tid = threadIdx.x;
  const int lane = tid & 63, w = tid >> 6;
  const int wm = w >> 1, wn = w & 1;
  const int mBase = blockIdx.x * BM, nBase = blockIdx.y * BN;
  const int k0 = blockIdx.z * kLen;
  const int nIter = kLen >> 5;            // even (16) at every call site

  f32x4 acc[FM][FN];
#pragma unroll
  for (int i = 0; i < FM; i++)
#pragma unroll
    for (int j = 0; j < FN; j++) acc[i][j] = {0.f, 0.f, 0.f, 0.f};

  // stage: chunk u (16B) covers (row = u>>2, sub = u&3) of the 32-wide K-slice.
  // Chunks c < BM/16 load A, the rest load B.  LDS dest is wave-uniform.
  auto stage = [&](int buf, int k) {
#pragma unroll
    for (int p = 0; p < PASS; p++) {
      int c = p * 4 + w;
      int u = c * 64 + lane;
      if (c < BM / 16) {
        int row = u >> 2, sub = u & 3;
        gload16(A + (size_t)(mBase + row) * K + k + sub * 8,
                (char*)As[buf] + c * 1024);
      } else {
        int u2 = u - BM * 4;
        int row = u2 >> 2, sub = u2 & 3;
        gload16(Bm + (size_t)(nBase + row) * K + k + sub * 8,
                (char*)Bs[buf] + (c - BM / 16) * 1024);
      }
    }
  };
  auto compute = [&](int cur) {
    bf16x8 af[FM], bfr[FN];
#pragma unroll
    for (int i = 0; i < FM; i++)
      af[i] = *(const bf16x8*)(As[cur] + (wm * WM + i * 16 + (lane & 15)) * 32 + (lane >> 4) * 8);
#pragma unroll
    for (int j = 0; j < FN; j++)
      bfr[j] = *(const bf16x8*)(Bs[cur] + (wn * WN + j * 16 + (lane & 15)) * 32 + (lane >> 4) * 8);
#pragma unroll
    for (int i = 0; i < FM; i++)
#pragma unroll
      for (int j = 0; j < FN; j++)
        acc[i][j] = __builtin_amdgcn_mfma_f32_16x16x32_bf16(af[i], bfr[j], acc[i][j], 0, 0, 0);
  };

  // prologue: stage tiles 0 and 1; keep tile 1 in flight across the barrier.
  stage(0, k0);
  if (nIter > 1) {
    stage(1, k0 + 32);
    bar_keep<KEEP>();
  } else {
    bar_keep<0>();
  }

  // main loop, pair-unrolled; LDS buffers rotate mod 3.
  int c0 = 0, c1 = 1, c2 = 2;
  for (int t = 0; t < nIter; t += 2) {
    {
      const bool more2 = (t + 2 < nIter);
      if (more2) stage(c2, k0 + (t + 2) * 32);
      compute(c0);
      if (more2) bar_keep<KEEP>(); else bar_keep<0>();
    }
    {
      const bool more3 = (t + 3 < nIter);
      if (more3) stage(c0, k0 + (t + 3) * 32);
      compute(c1);
      if (more3) bar_keep<KEEP>(); else bar_keep<0>();
    }
    int tmp = c2; c2 = c1; c1 = c0; c0 = tmp;
  }

  if constexpr (MODE == 0) {
    float* Cz = C + (size_t)blockIdx.z * MN;
#pragma unroll
    for (int i = 0; i < FM; i++)
#pragma unroll
      for (int j = 0; j < FN; j++) {
        int n  = nBase + wn * WN + j * 16 + (lane & 15);
        int mB = mBase + wm * WM + i * 16 + ((lane >> 4) << 2);
#pragma unroll
        for (int r = 0; r < 4; r++)
          Cz[(size_t)(mB + r) * N + n] = acc[i][j][r];
      }
  } else if constexpr (MODE == 1) {
    bf16* Cb = (bf16*)C;
#pragma unroll
    for (int i = 0; i < FM; i++)
#pragma unroll
      for (int j = 0; j < FN; j++) {
        int n  = nBase + wn * WN + j * 16 + (lane & 15);
        float bo = bias[n];
        int mB = mBase + wm * WM + i * 16 + ((lane >> 4) << 2);
#pragma unroll
        for (int r = 0; r < 4; r++) {
          float x = acc[i][j][r] + bo;
          if constexpr (ACT == 1)
            x = 0.5f * x * (1.f + erff(x * 0.70710678118654752f));
          Cb[(size_t)(mB + r) * N + n] = (bf16)x;
        }
      }
  } else {
    float lsum = 0.f;
#pragma unroll
    for (int i = 0; i < FM; i++)
#pragma unroll
      for (int j = 0; j < FN; j++) {
        int n  = nBase + wn * WN + j * 16 + (lane & 15);
        float bo = bias[n];
        int mB = mBase + wm * WM + i * 16 + ((lane >> 4) << 2);
#pragma unroll
        for (int r = 0; r < 4; r++) {
          float d = acc[i][j][r] + bo - x0[(size_t)(mB + r) * N + n];
          lsum += d * d;
        }
      }
    for (int off = 32; off > 0; off >>= 1) lsum += __shfl_down(lsum, off, 64);
    if (lane == 0) lred[w] = lsum;
    __syncthreads();
    if (tid == 0)
      atomicAdd(lossOut,
                (lred[0] + lred[1] + lred[2] + lred[3]) * (1.f / 4194304.f));
  }
}

// ------------- h = sum_32 partials + b_in + time-embed; write fp32 + bf16
__global__ __launch_bounds__(512) void k_epi_h(const float* __restrict__ P,
                                               const float* __restrict__ t,
                                               const float* __restrict__ W_t1,
                                               const float* __restrict__ b_t1,
                                               const float* __restrict__ W_t2,
                                               const float* __restrict__ b_t2,
                                               const float* __restrict__ b_in,
                                               float* __restrict__ h_f32,
                                               bf16* __restrict__ h_b) {
  int b = blockIdx.x, d = threadIdx.x;
  __shared__ float s[32];
  if (d < 32) {
    float z = t[b] * W_t1[d] + b_t1[d];   // t_norm == t
    s[d] = z / (1.f + expf(-z));          // silu
  }
  __syncthreads();
  int i = b * Dd + d;
  float v = b_in[d] + b_t2[d];
#pragma unroll
  for (int sp = 0; sp < 32; sp++) v += P[sp * (Bb * Dd) + i];
#pragma unroll
  for (int j = 0; j < 32; j++) v += s[j] * W_t2[d * 32 + j];
  h_f32[i] = v;
  h_b[i] = (bf16)v;
}

// -------- LayerNorm over D=512: x = base + sum_NS add + bias; y = LN(x)*g+be
template <int NS>
__global__ __launch_bounds__(512) void k_ln(const float* __restrict__ base,
                                            const float* __restrict__ add,
                                            const float* __restrict__ bias,
                                            const float* __restrict__ g,
                                            const float* __restrict__ be,
                                            float* __restrict__ out_f32,
                                            bf16* __restrict__ out_b) {
  int b = blockIdx.x, d = threadIdx.x;
  __shared__ float red[16];
  int i = b * Dd + d;
  float x = base[i] + bias[d];
#pragma unroll
  for (int sp = 0; sp < NS; sp++) x += add[sp * (Bb * Dd) + i];
  int w = d >> 6, lane = d & 63;
  float s = x;
  for (int off = 32; off > 0; off >>= 1) s += __shfl_down(s, off, 64);
  if (lane == 0) red[w] = s;
  __syncthreads();
  if (d == 0) {
    float tot = 0.f;
    for (int q = 0; q < 8; q++) tot += red[q];
    red[8] = tot * (1.f / 512.f);
  }
  __syncthreads();
  float mu = red[8];
  float c = x - mu;
  float s2 = c * c;
  for (int off = 32; off > 0; off >>= 1) s2 += __shfl_down(s2, off, 64);
  if (lane == 0) red[w] = s2;
  __syncthreads();
  if (d == 0) {
    float tot = 0.f;
    for (int q = 0; q < 8; q++) tot += red[q];
    red[8] = tot * (1.f / 512.f);
  }
  __syncthreads();
  float var = red[8];
  float y = c * rsqrtf(var + 1e-5f) * g[d] + be[d];
  if (out_f32) out_f32[i] = y;
  out_b[i] = (bf16)y;
}

// ======================================================================= host
extern "C" void kernel_launch(void* const* d_in, const int* in_sizes, int n_in,
                              void* d_out, int out_size, void* d_ws, size_t ws_size,
                              hipStream_t stream) {
  const float* x0    = (const float*)d_in[0];
  const float* t     = (const float*)d_in[1];
  const float* Lv    = (const float*)d_in[2];
  const float* W_in  = (const float*)d_in[3];
  const float* b_in  = (const float*)d_in[4];
  const float* W_out = (const float*)d_in[5];
  const float* b_out = (const float*)d_in[6];
  const float* W_qkv = (const float*)d_in[7];
  const float* b_qkv = (const float*)d_in[8];
  const float* W_o   = (const float*)d_in[9];
  const float* b_o   = (const float*)d_in[10];
  const float* g1    = (const float*)d_in[11];
  const float* be1   = (const float*)d_in[12];
  const float* g2    = (const float*)d_in[13];
  const float* be2   = (const float*)d_in[14];
  const float* W_f1  = (const float*)d_in[15];
  const float* b_f1  = (const float*)d_in[16];
  const float* W_f2  = (const float*)d_in[17];
  const float* b_f2  = (const float*)d_in[18];
  const float* W_t1  = (const float*)d_in[19];
  const float* b_t1  = (const float*)d_in[20];
  const float* W_t2  = (const float*)d_in[21];
  const float* b_t2  = (const float*)d_in[22];
  const int* L_rows  = (const int*)d_in[23];
  const int* L_cols  = (const int*)d_in[24];

  size_t off = 0;
  char* ws = (char*)d_ws;
  auto carve = [&](size_t bytes) -> void* {
    void* p = ws + off;
    off += (bytes + 255) & ~(size_t)255;
    return p;
  };

  bf16* W_v_b    = (bf16*)carve((size_t)Dd * Dd * 2);
  bf16* W_o_b    = (bf16*)carve((size_t)Dd * Dd * 2);
  bf16* W_f1_b   = (bf16*)carve((size_t)DFf * Dd * 2);
  bf16* W_f2_b   = (bf16*)carve((size_t)Dd * DFf * 2);
  bf16* W_in_b   = (bf16*)carve((size_t)Dd * Nn * 2);        // 16.8 MB
  bf16* W_out_b  = (bf16*)carve((size_t)Nn * Dd * 2);        // 16.8 MB
  bf16* x0T_b    = (bf16*)carve((size_t)Nn * Bb * 2);
  bf16* Lx_b     = (bf16*)carve((size_t)Nn * Bb * 2);
  bf16* xt_b     = (bf16*)carve((size_t)Bb * Nn * 2);
  float* p_h     = (float*)carve((size_t)32 * Bb * Dd * 4);  // 16 MB
  float* p_at    = (float*)carve((size_t)Bb * Dd * 4);
  float* p_f2    = (float*)carve((size_t)4 * Bb * Dd * 4);
  float* h_f32   = (float*)carve((size_t)Bb * Dd * 4);
  bf16* h_b      = (bf16*)carve((size_t)Bb * Dd * 2);
  bf16* v_b      = (bf16*)carve((size_t)Bb * Dd * 2);
  float* hln_f32 = (float*)carve((size_t)Bb * Dd * 4);
  bf16* hln_b    = (bf16*)carve((size_t)Bb * Dd * 2);
  bf16* f1_b     = (bf16*)carve((size_t)Bb * DFf * 2);
  bf16* h2_b     = (bf16*)carve((size_t)Bb * Dd * 2);
  int* counts    = (int*)carve((size_t)Nn * 4);
  unsigned* ents = (unsigned*)carve((size_t)Nn * SLOT * 4);  // 4.2 MB
  (void)in_sizes; (void)n_in; (void)out_size; (void)ws_size; (void)Lv;

  hipMemsetAsync(counts, 0, (size_t)Nn * 4, stream);

  // prep: weight cvt (x5, no W_out) | x0 transpose | nnz bucketing;
  // also zeroes the output loss scalar.
  k_prep<<<PREP_BLKS, 256, 0, stream>>>(
      W_qkv + (size_t)2 * Dd * Dd, W_o, W_f1, W_f2, W_in,
      W_v_b, W_o_b, W_f1_b, W_f2_b, W_in_b,
      x0, x0T_b, L_rows, L_cols, Lv, counts, ents, (float*)d_out);

  k_lx<<<Nn / 4, 256, 0, stream>>>((const bf16x4*)x0T_b, counts, ents,
                                   (bf16x4*)Lx_b);
  k_combine<<<dim3(256, 4), 256, 0, stream>>>(x0, Lx_b, t, xt_b);

  // h = x_t @ W_in^T   (M=256,N=512,K=16384, split-K=32; BM=128 halves B re-reads)
  gemm_tn<128, 64, 0><<<dim3(2, 8, 32), 256, 0, stream>>>(
      xt_b, W_in_b, p_h, Dd, Nn, 512, Bb * Dd, nullptr, nullptr, nullptr,
      nullptr, nullptr, 0);
  k_epi_h<<<Bb, 512, 0, stream>>>(p_h, t, W_t1, b_t1, W_t2, b_t2, b_in, h_f32, h_b);

  // v = h @ W_qkv_v^T + bias  (128 gemm blocks + 1024 W_out-cvt rider blocks:
  // the rider streams on the half of the machine the small GEMM leaves idle)
  gemm_tn<32, 32, 1, 0, 16><<<dim3(8, 16 + 128, 1), 256, 0, stream>>>(
      h_b, W_v_b, (float*)v_b, Dd, Dd, 512, 0, b_qkv + 2 * Dd, nullptr, nullptr,
      W_out, W_out_b, 0);

  // attn_out = v @ W_o^T  (bias folded into LN; second half of W_out cvt rides)
  gemm_tn<32, 32, 0, 0, 16><<<dim3(8, 16 + 128, 1), 256, 0, stream>>>(
      v_b, W_o_b, p_at, Dd, Dd, 512, 0, nullptr, nullptr, nullptr,
      W_out, W_out_b, WOUT_VEC4 / 2);
  k_ln<1><<<Bb, 512, 0, stream>>>(h_f32, p_at, b_o, g1, be1, hln_f32, hln_b);

  // ff1 = gelu(hln @ W_f1^T + b_f1)  (32x32 tiles -> 512 blocks)
  gemm_tn<32, 32, 1, 1><<<dim3(8, 64, 1), 256, 0, stream>>>(
      hln_b, W_f1_b, (float*)f1_b, DFf, Dd, 512, 0, b_f1, nullptr, nullptr,
      nullptr, nullptr, 0);

  // ff2 = ff1 @ W_f2^T  (K=2048, split-K=4, 32x32 tiles -> 512 blocks)
  gemm_tn<32, 32, 0><<<dim3(8, 16, 4), 256, 0, stream>>>(
      f1_b, W_f2_b, p_f2, Dd, DFf, 512, Bb * Dd, nullptr, nullptr, nullptr,
      nullptr, nullptr, 0);
  k_ln<4><<<Bb, 512, 0, stream>>>(hln_f32, p_f2, b_f2, g2, be2, nullptr, h2_b);

  // pred = h2 @ W_out^T + b_out, fused+scaled loss straight into d_out
  gemm_tn<128, 64, 2><<<dim3(2, 256, 1), 256, 0, stream>>>(
      h2_b, W_out_b, nullptr, Nn, Dd, 512, 0, b_out, x0, (float*)d_out,
      nullptr, nullptr, 0);
}

// Round 12
// 283.120 us; speedup vs baseline: 1.0272x; 1.0272x over previous
//
#include <hip/hip_runtime.h>
#include <math.h>

// Problem constants
#define Bb   256
#define Nn   16384
#define Dd   512
#define NNZn 540672
#define DFf  2048
#define SLOT 64    // packed bucket width (max row count ~58 for Binom(540672,1/16384))

// k_prep block counts (roles interleaved across dispatch order, r5/r10-validated)
#define CVT_BLKS 4736   // all six weights: 4,849,664 vec4 / 1024
#define TR_BLKS  1024
#define BK_BLKS  2112   // 540672 / 256 exactly
#define PREP_BLKS (CVT_BLKS + TR_BLKS + BK_BLKS)   // 7872

// cvt segment boundaries (vec4 units)
#define C1 65536      // W_v
#define C2 131072     // W_o
#define C3 393216     // W_f1
#define C4 655360     // W_f2
#define C5 2752512    // W_in
#define C6 4849664    // W_out

typedef __bf16 bf16;
typedef __bf16 bf16x4 __attribute__((ext_vector_type(4)));
typedef __bf16 bf16x8 __attribute__((ext_vector_type(8)));
typedef float  f32x4  __attribute__((ext_vector_type(4)));

// ---------------------------------------------------------------- async G->LDS
__device__ __forceinline__ void gload16(const void* g, void* l) {
  __builtin_amdgcn_global_load_lds(
      (const __attribute__((address_space(1))) unsigned int*)g,
      (__attribute__((address_space(3))) unsigned int*)l, 16, 0, 0);
}

// Counted-vmcnt barrier (T4): drain all but NK outstanding VMEM ops, then
// raw s_barrier.  NK>0 keeps the freshly issued tile-(t+2) stage in flight.
template <int NK>
__device__ __forceinline__ void bar_keep() {
  asm volatile("s_waitcnt vmcnt(%0) lgkmcnt(0)" :: "n"(NK) : "memory");
  __builtin_amdgcn_s_barrier();
}

__device__ __forceinline__ float f16_of(unsigned e) {
  unsigned short us = (unsigned short)(e & 0xffff);
  _Float16 h;
  __builtin_memcpy(&h, &us, 2);
  return (float)h;
}

// ---- merged prep: weight cvt (x6) | x0 transpose | nnz bucketing (packed).
// Roles are INTERLEAVED in blockIdx order: every 3rd block (while they last)
// is a latency-bound bucketing block, so its scatter/atomic latency overlaps
// the streaming cvt/transpose BW instead of running as a straggler tail.
// Also zeroes d_loss (k_prep is always the first kernel).
__global__ __launch_bounds__(256) void k_prep(
    const float* __restrict__ w_v, const float* __restrict__ w_o,
    const float* __restrict__ w_f1, const float* __restrict__ w_f2,
    const float* __restrict__ w_in, const float* __restrict__ w_out,
    bf16* __restrict__ o_v, bf16* __restrict__ o_o,
    bf16* __restrict__ o_f1, bf16* __restrict__ o_f2,
    bf16* __restrict__ o_in, bf16* __restrict__ o_out,
    const float* __restrict__ x0, bf16* __restrict__ x0T,
    const int* __restrict__ rows, const int* __restrict__ cols,
    const float* __restrict__ vals,
    int* __restrict__ counts, unsigned* __restrict__ ents,
    float* __restrict__ d_loss) {
  __shared__ float tile[64][65];
  int blk = blockIdx.x;
  if (blk == 0 && threadIdx.x == 0) *d_loss = 0.f;
  int q = blk / 3;
  if ((blk % 3) == 0 && q < BK_BLKS) {
    // ---- bucketing role (2112 virtual blocks, spread across dispatch order)
    int i = q * 256 + threadIdx.x;  // exact: 540672
    int r = rows[i];
    int p = atomicAdd(&counts[r], 1);
    if (p < SLOT) {
      _Float16 hv = (_Float16)vals[i];
      unsigned short us;
      __builtin_memcpy(&us, &hv, 2);
      ents[(size_t)r * SLOT + p] = ((unsigned)cols[i] << 16) | (unsigned)us;
    }
  } else {
    int sB = (blk + 2) / 3; if (sB > BK_BLKS) sB = BK_BLKS;  // scatter blocks before blk
    int o = blk - sB;       // 0..5759
    if (o < CVT_BLKS) {
      int v0i = o * 1024 + threadIdx.x;
#pragma unroll
      for (int j = 0; j < 4; j++) {
        int v = v0i + j * 256;
        const float* s; bf16* d; int base;
        if (v < C2)      { if (v < C1) { s = w_v;  d = o_v;  base = 0;  }
                           else        { s = w_o;  d = o_o;  base = C1; } }
        else if (v < C4) { if (v < C3) { s = w_f1; d = o_f1; base = C2; }
                           else        { s = w_f2; d = o_f2; base = C3; } }
        else             { if (v < C5) { s = w_in; d = o_in; base = C4; }
                           else        { s = w_out; d = o_out; base = C5; } }
        int idx = (v - base) * 4;
        float4 x = *(const float4*)(s + idx);
        bf16x4 ob;
        ob[0] = (bf16)x.x; ob[1] = (bf16)x.y; ob[2] = (bf16)x.z; ob[3] = (bf16)x.w;
        *(bf16x4*)(d + idx) = ob;
      }
    } else {
      int bx = o - CVT_BLKS;
      int n0 = (bx & 255) * 64, b0 = (bx >> 8) * 64;
      int tx = threadIdx.x & 63, ty = threadIdx.x >> 6;   // ty 0..3
#pragma unroll
      for (int i = 0; i < 16; i++) {
        int bl = ty * 16 + i;
        tile[bl][tx] = x0[(size_t)(b0 + bl) * Nn + n0 + tx];
      }
      __syncthreads();
#pragma unroll
      for (int i = 0; i < 16; i++) {
        int nl = ty * 16 + i;
        x0T[(size_t)(n0 + nl) * Bb + b0 + tx] = (bf16)tile[tx][nl];
      }
    }
  }
}

// ---- Lx[r][:] = sum_j val_j * x0T[col_j][:].  One WAVE per row; each lane
// holds 4 batch elems (bf16x4, 8 B) -> one gather instr = full 512 B row.
// Entries packed: col<<16 | fp16(val).  4-deep gather ILP.
__global__ __launch_bounds__(256) void k_lx(const bf16x4* __restrict__ x0T4,
                                            const int* __restrict__ counts,
                                            const unsigned* __restrict__ ents,
                                            bf16x4* __restrict__ Lx4) {
  int w = threadIdx.x >> 6, lane = threadIdx.x & 63;
  int r = blockIdx.x * 4 + w;
  __shared__ unsigned esm[4][64];
  int cnt = counts[r];
  if (cnt > SLOT) cnt = SLOT;
  const unsigned* ep = ents + (size_t)r * SLOT;
  float a0 = 0.f, a1 = 0.f, a2 = 0.f, a3 = 0.f;
  float b0 = 0.f, b1 = 0.f, b2 = 0.f, b3 = 0.f;
  float c0 = 0.f, c1 = 0.f, c2 = 0.f, c3 = 0.f;
  float d0 = 0.f, d1 = 0.f, d2 = 0.f, d3 = 0.f;
  for (int base = 0; base < cnt; base += 64) {
    int m = cnt - base; if (m > 64) m = 64;
    if (lane < m) esm[w][lane] = ep[base + lane];
    int i = 0;
    for (; i + 3 < m; i += 4) {
      unsigned e0 = esm[w][i],     e1 = esm[w][i + 1];
      unsigned e2 = esm[w][i + 2], e3 = esm[w][i + 3];
      bf16x4 xv0 = x0T4[(size_t)(e0 >> 16) * 64 + lane];
      bf16x4 xv1 = x0T4[(size_t)(e1 >> 16) * 64 + lane];
      bf16x4 xv2 = x0T4[(size_t)(e2 >> 16) * 64 + lane];
      bf16x4 xv3 = x0T4[(size_t)(e3 >> 16) * 64 + lane];
      float v0 = f16_of(e0), v1 = f16_of(e1), v2 = f16_of(e2), v3 = f16_of(e3);
      a0 += v0 * (float)xv0[0]; a1 += v0 * (float)xv0[1];
      a2 += v0 * (float)xv0[2]; a3 += v0 * (float)xv0[3];
      b0 += v1 * (float)xv1[0]; b1 += v1 * (float)xv1[1];
      b2 += v1 * (float)xv1[2]; b3 += v1 * (float)xv1[3];
      c0 += v2 * (float)xv2[0]; c1 += v2 * (float)xv2[1];
      c2 += v2 * (float)xv2[2]; c3 += v2 * (float)xv2[3];
      d0 += v3 * (float)xv3[0]; d1 += v3 * (float)xv3[1];
      d2 += v3 * (float)xv3[2]; d3 += v3 * (float)xv3[3];
    }
    for (; i < m; i++) {
      unsigned e0 = esm[w][i];
      bf16x4 xv0 = x0T4[(size_t)(e0 >> 16) * 64 + lane];
      float v0 = f16_of(e0);
      a0 += v0 * (float)xv0[0]; a1 += v0 * (float)xv0[1];
      a2 += v0 * (float)xv0[2]; a3 += v0 * (float)xv0[3];
    }
  }
  bf16x4 o;
  o[0] = (bf16)(a0 + b0 + c0 + d0); o[1] = (bf16)(a1 + b1 + c1 + d1);
  o[2] = (bf16)(a2 + b2 + c2 + d2); o[3] = (bf16)(a3 + b3 + c3 + d3);
  Lx4[(size_t)r * 64 + lane] = o;
}

// ---- x_t[b][n] = x0[b][n] - 0.5*t[b]*Lx[n][b]   (bf16, B-major output).
// Reads BOTH x0 and Lx from the bf16 [n][b]-layout buffers (x0T, Lx) --
// 25 MB moved instead of 92 MB (x0 fp32 re-read eliminated).  The bf16
// rounding of x0 here is the same order as the bf16 rounding already
// applied to x_t for the MFMA GEMM.
__global__ __launch_bounds__(256) void k_combine(const bf16* __restrict__ x0T,
                                                 const bf16* __restrict__ Lx,
                                                 const float* __restrict__ t,
                                                 bf16* __restrict__ xt) {
  __shared__ float xs[64][65];
  __shared__ float lxs[64][65];
  int n0 = blockIdx.x * 64, b0 = blockIdx.y * 64;
  int tx = threadIdx.x & 63, ty = threadIdx.x >> 6;
#pragma unroll
  for (int i = 0; i < 16; i++) {
    int nl = ty * 16 + i;
    size_t base = (size_t)(n0 + nl) * Bb + b0 + tx;
    xs[nl][tx]  = (float)x0T[base];
    lxs[nl][tx] = (float)Lx[base];
  }
  __syncthreads();
#pragma unroll
  for (int i = 0; i < 16; i++) {
    int bl = ty * 16 + i;
    int b  = b0 + bl;
    float tc = t[b] * 0.5f;   // T_MAX
    float v = xs[tx][bl] - tc * lxs[tx][bl];
    xt[(size_t)b * Nn + n0 + tx] = (bf16)v;
  }
}

// ------------------------------------------------------------- bf16 TN GEMM
// C[m][n] = sum_k A[m][k]*Bm[n][k].  All-bf16, all-gload16 staging.
// Depth-2 prefetch (T3/T4): triple-buffered LDS; stage(t+2) issued at iter t;
// counted-vmcnt barrier drains only tile t+1, keeps tile t+2 in flight.
//   MODE 0: store fp32 split-K partial at z*MN
//   MODE 1: direct bf16 store of acc+bias (ACT=1: exact gelu) -> C is bf16*
//   MODE 2: fused loss sum((C+bias-x0)^2) * 1/(B*N), one atomic per block
//           directly into the output scalar (zeroed by k_prep)
template <int BM, int BN, int MODE, int ACT = 0>
__global__ __launch_bounds__(256) void gemm_tn(
    const bf16* __restrict__ A, const bf16* __restrict__ Bm,
    float* __restrict__ C, int N, int K, int kLen, int MN,
    const float* __restrict__ bias, const float* __restrict__ x0,
    float* __restrict__ lossOut) {
  constexpr int WM = BM / 2, WN = BN / 2, FM = WM / 16, FN = WN / 16;
  constexpr int PASS = (BM + BN) / 64;  // 64B-chunk groups per stage (per wave)
  constexpr int KEEP = PASS;
  __shared__ __align__(16) bf16 As[3][BM * 32];
  __shared__ __align__(16) bf16 Bs[3][BN * 32];
  __shared__ float lred[4];
  const int tid = threadIdx.x;
  const int lane = tid & 63, w = tid >> 6;
  const int wm = w >> 1, wn = w & 1;
  const int mBase = blockIdx.x * BM, nBase = blockIdx.y * BN;
  const int k0 = blockIdx.z * kLen;
  const int nIter = kLen >> 5;            // even (16) at every call site

  f32x4 acc[FM][FN];
#pragma unroll
  for (int i = 0; i < FM; i++)
#pragma unroll
    for (int j = 0; j < FN; j++) acc[i][j] = {0.f, 0.f, 0.f, 0.f};

  // stage: chunk u (16B) covers (row = u>>2, sub = u&3) of the 32-wide K-slice.
  // Chunks c < BM/16 load A, the rest load B.  LDS dest is wave-uniform.
  auto stage = [&](int buf, int k) {
#pragma unroll
    for (int p = 0; p < PASS; p++) {
      int c = p * 4 + w;
      int u = c * 64 + lane;
      if (c < BM / 16) {
        int row = u >> 2, sub = u & 3;
        gload16(A + (size_t)(mBase + row) * K + k + sub * 8,
                (char*)As[buf] + c * 1024);
      } else {
        int u2 = u - BM * 4;
        int row = u2 >> 2, sub = u2 & 3;
        gload16(Bm + (size_t)(nBase + row) * K + k + sub * 8,
                (char*)Bs[buf] + (c - BM / 16) * 1024);
      }
    }
  };
  auto compute = [&](int cur) {
    bf16x8 af[FM], bfr[FN];
#pragma unroll
    for (int i = 0; i < FM; i++)
      af[i] = *(const bf16x8*)(As[cur] + (wm * WM + i * 16 + (lane & 15)) * 32 + (lane >> 4) * 8);
#pragma unroll
    for (int j = 0; j < FN; j++)
      bfr[j] = *(const bf16x8*)(Bs[cur] + (wn * WN + j * 16 + (lane & 15)) * 32 + (lane >> 4) * 8);
#pragma unroll
    for (int i = 0; i < FM; i++)
#pragma unroll
      for (int j = 0; j < FN; j++)
        acc[i][j] = __builtin_amdgcn_mfma_f32_16x16x32_bf16(af[i], bfr[j], acc[i][j], 0, 0, 0);
  };

  // prologue: stage tiles 0 and 1; keep tile 1 in flight across the barrier.
  stage(0, k0);
  if (nIter > 1) {
    stage(1, k0 + 32);
    bar_keep<KEEP>();
  } else {
    bar_keep<0>();
  }

  // main loop, pair-unrolled; LDS buffers rotate mod 3.
  int c0 = 0, c1 = 1, c2 = 2;
  for (int t = 0; t < nIter; t += 2) {
    {
      const bool more2 = (t + 2 < nIter);
      if (more2) stage(c2, k0 + (t + 2) * 32);
      compute(c0);
      if (more2) bar_keep<KEEP>(); else bar_keep<0>();
    }
    {
      const bool more3 = (t + 3 < nIter);
      if (more3) stage(c0, k0 + (t + 3) * 32);
      compute(c1);
      if (more3) bar_keep<KEEP>(); else bar_keep<0>();
    }
    int tmp = c2; c2 = c1; c1 = c0; c0 = tmp;
  }

  if constexpr (MODE == 0) {
    float* Cz = C + (size_t)blockIdx.z * MN;
#pragma unroll
    for (int i = 0; i < FM; i++)
#pragma unroll
      for (int j = 0; j < FN; j++) {
        int n  = nBase + wn * WN + j * 16 + (lane & 15);
        int mB = mBase + wm * WM + i * 16 + ((lane >> 4) << 2);
#pragma unroll
        for (int r = 0; r < 4; r++)
          Cz[(size_t)(mB + r) * N + n] = acc[i][j][r];
      }
  } else if constexpr (MODE == 1) {
    bf16* Cb = (bf16*)C;
#pragma unroll
    for (int i = 0; i < FM; i++)
#pragma unroll
      for (int j = 0; j < FN; j++) {
        int n  = nBase + wn * WN + j * 16 + (lane & 15);
        float bo = bias[n];
        int mB = mBase + wm * WM + i * 16 + ((lane >> 4) << 2);
#pragma unroll
        for (int r = 0; r < 4; r++) {
          float x = acc[i][j][r] + bo;
          if constexpr (ACT == 1)
            x = 0.5f * x * (1.f + erff(x * 0.70710678118654752f));
          Cb[(size_t)(mB + r) * N + n] = (bf16)x;
        }
      }
  } else {
    float lsum = 0.f;
#pragma unroll
    for (int i = 0; i < FM; i++)
#pragma unroll
      for (int j = 0; j < FN; j++) {
        int n  = nBase + wn * WN + j * 16 + (lane & 15);
        float bo = bias[n];
        int mB = mBase + wm * WM + i * 16 + ((lane >> 4) << 2);
#pragma unroll
        for (int r = 0; r < 4; r++) {
          float d = acc[i][j][r] + bo - x0[(size_t)(mB + r) * N + n];
          lsum += d * d;
        }
      }
    for (int off = 32; off > 0; off >>= 1) lsum += __shfl_down(lsum, off, 64);
    if (lane == 0) lred[w] = lsum;
    __syncthreads();
    if (tid == 0)
      atomicAdd(lossOut,
                (lred[0] + lred[1] + lred[2] + lred[3]) * (1.f / 4194304.f));
  }
}

// ------------- h = sum_32 partials + b_in + time-embed; write fp32 + bf16
__global__ __launch_bounds__(512) void k_epi_h(const float* __restrict__ P,
                                               const float* __restrict__ t,
                                               const float* __restrict__ W_t1,
                                               const float* __restrict__ b_t1,
                                               const float* __restrict__ W_t2,
                                               const float* __restrict__ b_t2,
                                               const float* __restrict__ b_in,
                                               float* __restrict__ h_f32,
                                               bf16* __restrict__ h_b) {
  int b = blockIdx.x, d = threadIdx.x;
  __shared__ float s[32];
  if (d < 32) {
    float z = t[b] * W_t1[d] + b_t1[d];   // t_norm == t
    s[d] = z / (1.f + expf(-z));          // silu
  }
  __syncthreads();
  int i = b * Dd + d;
  float v = b_in[d] + b_t2[d];
#pragma unroll
  for (int sp = 0; sp < 32; sp++) v += P[sp * (Bb * Dd) + i];
#pragma unroll
  for (int j = 0; j < 32; j++) v += s[j] * W_t2[d * 32 + j];
  h_f32[i] = v;
  h_b[i] = (bf16)v;
}

// -------- LayerNorm over D=512: x = base + sum_NS add + bias; y = LN(x)*g+be
template <int NS>
__global__ __launch_bounds__(512) void k_ln(const float* __restrict__ base,
                                            const float* __restrict__ add,
                                            const float* __restrict__ bias,
                                            const float* __restrict__ g,
                                            const float* __restrict__ be,
                                            float* __restrict__ out_f32,
                                            bf16* __restrict__ out_b) {
  int b = blockIdx.x, d = threadIdx.x;
  __shared__ float red[16];
  int i = b * Dd + d;
  float x = base[i] + bias[d];
#pragma unroll
  for (int sp = 0; sp < NS; sp++) x += add[sp * (Bb * Dd) + i];
  int w = d >> 6, lane = d & 63;
  float s = x;
  for (int off = 32; off > 0; off >>= 1) s += __shfl_down(s, off, 64);
  if (lane == 0) red[w] = s;
  __syncthreads();
  if (d == 0) {
    float tot = 0.f;
    for (int q = 0; q < 8; q++) tot += red[q];
    red[8] = tot * (1.f / 512.f);
  }
  __syncthreads();
  float mu = red[8];
  float c = x - mu;
  float s2 = c * c;
  for (int off = 32; off > 0; off >>= 1) s2 += __shfl_down(s2, off, 64);
  if (lane == 0) red[w] = s2;
  __syncthreads();
  if (d == 0) {
    float tot = 0.f;
    for (int q = 0; q < 8; q++) tot += red[q];
    red[8] = tot * (1.f / 512.f);
  }
  __syncthreads();
  float var = red[8];
  float y = c * rsqrtf(var + 1e-5f) * g[d] + be[d];
  if (out_f32) out_f32[i] = y;
  out_b[i] = (bf16)y;
}

// ======================================================================= host
extern "C" void kernel_launch(void* const* d_in, const int* in_sizes, int n_in,
                              void* d_out, int out_size, void* d_ws, size_t ws_size,
                              hipStream_t stream) {
  const float* x0    = (const float*)d_in[0];
  const float* t     = (const float*)d_in[1];
  const float* Lv    = (const float*)d_in[2];
  const float* W_in  = (const float*)d_in[3];
  const float* b_in  = (const float*)d_in[4];
  const float* W_out = (const float*)d_in[5];
  const float* b_out = (const float*)d_in[6];
  const float* W_qkv = (const float*)d_in[7];
  const float* b_qkv = (const float*)d_in[8];
  const float* W_o   = (const float*)d_in[9];
  const float* b_o   = (const float*)d_in[10];
  const float* g1    = (const float*)d_in[11];
  const float* be1   = (const float*)d_in[12];
  const float* g2    = (const float*)d_in[13];
  const float* be2   = (const float*)d_in[14];
  const float* W_f1  = (const float*)d_in[15];
  const float* b_f1  = (const float*)d_in[16];
  const float* W_f2  = (const float*)d_in[17];
  const float* b_f2  = (const float*)d_in[18];
  const float* W_t1  = (const float*)d_in[19];
  const float* b_t1  = (const float*)d_in[20];
  const float* W_t2  = (const float*)d_in[21];
  const float* b_t2  = (const float*)d_in[22];
  const int* L_rows  = (const int*)d_in[23];
  const int* L_cols  = (const int*)d_in[24];

  size_t off = 0;
  char* ws = (char*)d_ws;
  auto carve = [&](size_t bytes) -> void* {
    void* p = ws + off;
    off += (bytes + 255) & ~(size_t)255;
    return p;
  };

  bf16* W_v_b    = (bf16*)carve((size_t)Dd * Dd * 2);
  bf16* W_o_b    = (bf16*)carve((size_t)Dd * Dd * 2);
  bf16* W_f1_b   = (bf16*)carve((size_t)DFf * Dd * 2);
  bf16* W_f2_b   = (bf16*)carve((size_t)Dd * DFf * 2);
  bf16* W_in_b   = (bf16*)carve((size_t)Dd * Nn * 2);        // 16.8 MB
  bf16* W_out_b  = (bf16*)carve((size_t)Nn * Dd * 2);        // 16.8 MB
  bf16* x0T_b    = (bf16*)carve((size_t)Nn * Bb * 2);
  bf16* Lx_b     = (bf16*)carve((size_t)Nn * Bb * 2);
  bf16* xt_b     = (bf16*)carve((size_t)Bb * Nn * 2);
  float* p_h     = (float*)carve((size_t)32 * Bb * Dd * 4);  // 16 MB
  float* p_at    = (float*)carve((size_t)Bb * Dd * 4);
  float* p_f2    = (float*)carve((size_t)4 * Bb * Dd * 4);
  float* h_f32   = (float*)carve((size_t)Bb * Dd * 4);
  bf16* h_b      = (bf16*)carve((size_t)Bb * Dd * 2);
  bf16* v_b      = (bf16*)carve((size_t)Bb * Dd * 2);
  float* hln_f32 = (float*)carve((size_t)Bb * Dd * 4);
  bf16* hln_b    = (bf16*)carve((size_t)Bb * Dd * 2);
  bf16* f1_b     = (bf16*)carve((size_t)Bb * DFf * 2);
  bf16* h2_b     = (bf16*)carve((size_t)Bb * Dd * 2);
  int* counts    = (int*)carve((size_t)Nn * 4);
  unsigned* ents = (unsigned*)carve((size_t)Nn * SLOT * 4);  // 4.2 MB
  (void)in_sizes; (void)n_in; (void)out_size; (void)ws_size; (void)Lv;

  hipMemsetAsync(counts, 0, (size_t)Nn * 4, stream);

  // prep: weight cvt (x6) | x0 transpose | nnz bucketing (roles interleaved);
  // also zeroes the output loss scalar.
  k_prep<<<PREP_BLKS, 256, 0, stream>>>(
      W_qkv + (size_t)2 * Dd * Dd, W_o, W_f1, W_f2, W_in, W_out,
      W_v_b, W_o_b, W_f1_b, W_f2_b, W_in_b, W_out_b,
      x0, x0T_b, L_rows, L_cols, Lv, counts, ents, (float*)d_out);

  k_lx<<<Nn / 4, 256, 0, stream>>>((const bf16x4*)x0T_b, counts, ents,
                                   (bf16x4*)Lx_b);
  // x_t from bf16 [n][b] buffers (x0T + Lx) -- 25 MB moved vs 92 MB
  k_combine<<<dim3(256, 4), 256, 0, stream>>>(x0T_b, Lx_b, t, xt_b);

  // h = x_t @ W_in^T   (M=256,N=512,K=16384, split-K=32; BM=128 halves B re-reads)
  gemm_tn<128, 64, 0><<<dim3(2, 8, 32), 256, 0, stream>>>(
      xt_b, W_in_b, p_h, Dd, Nn, 512, Bb * Dd, nullptr, nullptr, nullptr);
  k_epi_h<<<Bb, 512, 0, stream>>>(p_h, t, W_t1, b_t1, W_t2, b_t2, b_in, h_f32, h_b);

  // v = h @ W_qkv_v^T + bias  (32x32 tiles -> 128 blocks)
  gemm_tn<32, 32, 1><<<dim3(8, 16, 1), 256, 0, stream>>>(
      h_b, W_v_b, (float*)v_b, Dd, Dd, 512, 0, b_qkv + 2 * Dd, nullptr, nullptr);

  // attn_out = v @ W_o^T  (bias folded into LN; 128 blocks)
  gemm_tn<32, 32, 0><<<dim3(8, 16, 1), 256, 0, stream>>>(
      v_b, W_o_b, p_at, Dd, Dd, 512, 0, nullptr, nullptr, nullptr);
  k_ln<1><<<Bb, 512, 0, stream>>>(h_f32, p_at, b_o, g1, be1, hln_f32, hln_b);

  // ff1 = gelu(hln @ W_f1^T + b_f1)  (32x32 tiles -> 512 blocks)
  gemm_tn<32, 32, 1, 1><<<dim3(8, 64, 1), 256, 0, stream>>>(
      hln_b, W_f1_b, (float*)f1_b, DFf, Dd, 512, 0, b_f1, nullptr, nullptr);

  // ff2 = ff1 @ W_f2^T  (K=2048, split-K=4, 32x32 tiles -> 512 blocks)
  gemm_tn<32, 32, 0><<<dim3(8, 16, 4), 256, 0, stream>>>(
      f1_b, W_f2_b, p_f2, Dd, DFf, 512, Bb * Dd, nullptr, nullptr, nullptr);
  k_ln<4><<<Bb, 512, 0, stream>>>(hln_f32, p_f2, b_f2, g2, be2, nullptr, h2_b);

  // pred = h2 @ W_out^T + b_out, fused+scaled loss straight into d_out
  gemm_tn<128, 64, 2><<<dim3(2, 256, 1), 256, 0, stream>>>(
      h2_b, W_out_b, nullptr, Nn, Dd, 512, 0, b_out, x0, (float*)d_out);
}

// Round 14
// 275.002 us; speedup vs baseline: 1.0575x; 1.0295x over previous
//
#include <hip/hip_runtime.h>
#include <math.h>

// Problem constants
#define Bb   256
#define Nn   16384
#define Dd   512
#define NNZn 540672
#define DFf  2048
#define SLOT 64    // packed bucket width (max row count ~58 for Binom(540672,1/16384))

// k_prep block counts (roles interleaved across dispatch order, r5/r10-validated)
#define CVT_BLKS 4736   // all six weights: 4,849,664 vec4 / 1024
#define TR_BLKS  1024
#define BK_BLKS  2112   // 540672 / 256 exactly
#define PREP_BLKS (CVT_BLKS + TR_BLKS + BK_BLKS)   // 7872

// cvt segment boundaries (vec4 units)
#define C1 65536      // W_v
#define C2 131072     // W_o
#define C3 393216     // W_f1
#define C4 655360     // W_f2
#define C5 2752512    // W_in
#define C6 4849664    // W_out

typedef __bf16 bf16;
typedef __bf16 bf16x4 __attribute__((ext_vector_type(4)));
typedef __bf16 bf16x8 __attribute__((ext_vector_type(8)));
typedef float  f32x2  __attribute__((ext_vector_type(2)));
typedef float  f32x4  __attribute__((ext_vector_type(4)));

// ---------------------------------------------------------------- async G->LDS
__device__ __forceinline__ void gload16(const void* g, void* l) {
  __builtin_amdgcn_global_load_lds(
      (const __attribute__((address_space(1))) unsigned int*)g,
      (__attribute__((address_space(3))) unsigned int*)l, 16, 0, 0);
}

// Counted-vmcnt barrier (T4): drain all but NK outstanding VMEM ops, then
// raw s_barrier.  NK>0 keeps the freshly issued tile-(t+2) stage in flight.
template <int NK>
__device__ __forceinline__ void bar_keep() {
  asm volatile("s_waitcnt vmcnt(%0) lgkmcnt(0)" :: "n"(NK) : "memory");
  __builtin_amdgcn_s_barrier();
}

__device__ __forceinline__ float f16_of(unsigned e) {
  unsigned short us = (unsigned short)(e & 0xffff);
  _Float16 h;
  __builtin_memcpy(&h, &us, 2);
  return (float)h;
}

// ---- merged prep: weight cvt (x6) | x0 transpose | nnz bucketing (packed).
// Roles are INTERLEAVED in blockIdx order: every 3rd block (while they last)
// is a latency-bound bucketing block, so its scatter/atomic latency overlaps
// the streaming cvt/transpose BW instead of running as a straggler tail.
// Transpose role emits BOTH x0T (bf16, for k_combine) and x0F (fp8 e4m3,
// the half-size gather table for k_lx).  Also zeroes d_loss.
__global__ __launch_bounds__(256) void k_prep(
    const float* __restrict__ w_v, const float* __restrict__ w_o,
    const float* __restrict__ w_f1, const float* __restrict__ w_f2,
    const float* __restrict__ w_in, const float* __restrict__ w_out,
    bf16* __restrict__ o_v, bf16* __restrict__ o_o,
    bf16* __restrict__ o_f1, bf16* __restrict__ o_f2,
    bf16* __restrict__ o_in, bf16* __restrict__ o_out,
    const float* __restrict__ x0, bf16* __restrict__ x0T,
    unsigned char* __restrict__ x0F,
    const int* __restrict__ rows, const int* __restrict__ cols,
    const float* __restrict__ vals,
    int* __restrict__ counts, unsigned* __restrict__ ents,
    float* __restrict__ d_loss) {
  __shared__ float tile[64][65];
  int blk = blockIdx.x;
  if (blk == 0 && threadIdx.x == 0) *d_loss = 0.f;
  int q = blk / 3;
  if ((blk % 3) == 0 && q < BK_BLKS) {
    // ---- bucketing role (2112 virtual blocks, spread across dispatch order)
    int i = q * 256 + threadIdx.x;  // exact: 540672
    int r = rows[i];
    int p = atomicAdd(&counts[r], 1);
    if (p < SLOT) {
      _Float16 hv = (_Float16)vals[i];
      unsigned short us;
      __builtin_memcpy(&us, &hv, 2);
      ents[(size_t)r * SLOT + p] = ((unsigned)cols[i] << 16) | (unsigned)us;
    }
  } else {
    int sB = (blk + 2) / 3; if (sB > BK_BLKS) sB = BK_BLKS;  // scatter blocks before blk
    int o = blk - sB;       // 0..5759
    if (o < CVT_BLKS) {
      int v0i = o * 1024 + threadIdx.x;
#pragma unroll
      for (int j = 0; j < 4; j++) {
        int v = v0i + j * 256;
        const float* s; bf16* d; int base;
        if (v < C2)      { if (v < C1) { s = w_v;  d = o_v;  base = 0;  }
                           else        { s = w_o;  d = o_o;  base = C1; } }
        else if (v < C4) { if (v < C3) { s = w_f1; d = o_f1; base = C2; }
                           else        { s = w_f2; d = o_f2; base = C3; } }
        else             { if (v < C5) { s = w_in; d = o_in; base = C4; }
                           else        { s = w_out; d = o_out; base = C5; } }
        int idx = (v - base) * 4;
        float4 x = *(const float4*)(s + idx);
        bf16x4 ob;
        ob[0] = (bf16)x.x; ob[1] = (bf16)x.y; ob[2] = (bf16)x.z; ob[3] = (bf16)x.w;
        *(bf16x4*)(d + idx) = ob;
      }
    } else {
      int bx = o - CVT_BLKS;
      int n0 = (bx & 255) * 64, b0 = (bx >> 8) * 64;
      int tx = threadIdx.x & 63, ty = threadIdx.x >> 6;   // ty 0..3
#pragma unroll
      for (int i = 0; i < 16; i++) {
        int bl = ty * 16 + i;
        tile[bl][tx] = x0[(size_t)(b0 + bl) * Nn + n0 + tx];
      }
      __syncthreads();
#pragma unroll
      for (int i = 0; i < 16; i++) {
        int nl = ty * 16 + i;
        float v = tile[tx][nl];
        size_t base = (size_t)(n0 + nl) * Bb + b0 + tx;
        x0T[base] = (bf16)v;
        unsigned p8 = __builtin_amdgcn_cvt_pk_fp8_f32(v, v, 0, false);
        x0F[base] = (unsigned char)(p8 & 0xff);
      }
    }
  }
}

// ---- Lx[r][:] = sum_j val_j * x0F[col_j][:].  One WAVE per row; each lane
// holds 4 batch elems packed as 4 fp8 bytes in one u32 -> one 4 B gather
// covers the full 256 B row (half the bytes of the bf16 table; k_lx is
// L3-BW bound on gather bytes).  Entries packed: col<<16 | fp16(val).
__global__ __launch_bounds__(256) void k_lx(const unsigned* __restrict__ x0F4,
                                            const int* __restrict__ counts,
                                            const unsigned* __restrict__ ents,
                                            bf16x4* __restrict__ Lx4) {
  int w = threadIdx.x >> 6, lane = threadIdx.x & 63;
  int r = blockIdx.x * 4 + w;
  __shared__ unsigned esm[4][64];
  int cnt = counts[r];
  if (cnt > SLOT) cnt = SLOT;
  const unsigned* ep = ents + (size_t)r * SLOT;
  float a0 = 0.f, a1 = 0.f, a2 = 0.f, a3 = 0.f;
  float b0 = 0.f, b1 = 0.f, b2 = 0.f, b3 = 0.f;
  float c0 = 0.f, c1 = 0.f, c2 = 0.f, c3 = 0.f;
  float d0 = 0.f, d1 = 0.f, d2 = 0.f, d3 = 0.f;
  for (int base = 0; base < cnt; base += 64) {
    int m = cnt - base; if (m > 64) m = 64;
    if (lane < m) esm[w][lane] = ep[base + lane];
    int i = 0;
    for (; i + 3 < m; i += 4) {
      unsigned e0 = esm[w][i],     e1 = esm[w][i + 1];
      unsigned e2 = esm[w][i + 2], e3 = esm[w][i + 3];
      unsigned u0 = x0F4[(size_t)(e0 >> 16) * 64 + lane];
      unsigned u1 = x0F4[(size_t)(e1 >> 16) * 64 + lane];
      unsigned u2 = x0F4[(size_t)(e2 >> 16) * 64 + lane];
      unsigned u3 = x0F4[(size_t)(e3 >> 16) * 64 + lane];
      float v0 = f16_of(e0), v1 = f16_of(e1), v2 = f16_of(e2), v3 = f16_of(e3);
      f32x2 l0 = __builtin_amdgcn_cvt_pk_f32_fp8(u0, false);
      f32x2 h0 = __builtin_amdgcn_cvt_pk_f32_fp8(u0, true);
      f32x2 l1 = __builtin_amdgcn_cvt_pk_f32_fp8(u1, false);
      f32x2 h1 = __builtin_amdgcn_cvt_pk_f32_fp8(u1, true);
      f32x2 l2 = __builtin_amdgcn_cvt_pk_f32_fp8(u2, false);
      f32x2 h2 = __builtin_amdgcn_cvt_pk_f32_fp8(u2, true);
      f32x2 l3 = __builtin_amdgcn_cvt_pk_f32_fp8(u3, false);
      f32x2 h3 = __builtin_amdgcn_cvt_pk_f32_fp8(u3, true);
      a0 += v0 * l0[0]; a1 += v0 * l0[1]; a2 += v0 * h0[0]; a3 += v0 * h0[1];
      b0 += v1 * l1[0]; b1 += v1 * l1[1]; b2 += v1 * h1[0]; b3 += v1 * h1[1];
      c0 += v2 * l2[0]; c1 += v2 * l2[1]; c2 += v2 * h2[0]; c3 += v2 * h2[1];
      d0 += v3 * l3[0]; d1 += v3 * l3[1]; d2 += v3 * h3[0]; d3 += v3 * h3[1];
    }
    for (; i < m; i++) {
      unsigned e0 = esm[w][i];
      unsigned u0 = x0F4[(size_t)(e0 >> 16) * 64 + lane];
      float v0 = f16_of(e0);
      f32x2 l0 = __builtin_amdgcn_cvt_pk_f32_fp8(u0, false);
      f32x2 h0 = __builtin_amdgcn_cvt_pk_f32_fp8(u0, true);
      a0 += v0 * l0[0]; a1 += v0 * l0[1]; a2 += v0 * h0[0]; a3 += v0 * h0[1];
    }
  }
  bf16x4 o;
  o[0] = (bf16)(a0 + b0 + c0 + d0); o[1] = (bf16)(a1 + b1 + c1 + d1);
  o[2] = (bf16)(a2 + b2 + c2 + d2); o[3] = (bf16)(a3 + b3 + c3 + d3);
  Lx4[(size_t)r * 64 + lane] = o;
}

// ---- x_t[b][n] = x0[b][n] - 0.5*t[b]*Lx[n][b]   (bf16, B-major output).
// Reads BOTH x0 and Lx from the bf16 [n][b]-layout buffers (x0T, Lx).
__global__ __launch_bounds__(256) void k_combine(const bf16* __restrict__ x0T,
                                                 const bf16* __restrict__ Lx,
                                                 const float* __restrict__ t,
                                                 bf16* __restrict__ xt) {
  __shared__ float xs[64][65];
  __shared__ float lxs[64][65];
  int n0 = blockIdx.x * 64, b0 = blockIdx.y * 64;
  int tx = threadIdx.x & 63, ty = threadIdx.x >> 6;
#pragma unroll
  for (int i = 0; i < 16; i++) {
    int nl = ty * 16 + i;
    size_t base = (size_t)(n0 + nl) * Bb + b0 + tx;
    xs[nl][tx]  = (float)x0T[base];
    lxs[nl][tx] = (float)Lx[base];
  }
  __syncthreads();
#pragma unroll
  for (int i = 0; i < 16; i++) {
    int bl = ty * 16 + i;
    int b  = b0 + bl;
    float tc = t[b] * 0.5f;   // T_MAX
    float v = xs[tx][bl] - tc * lxs[tx][bl];
    xt[(size_t)b * Nn + n0 + tx] = (bf16)v;
  }
}

// ------------------------------------------------------------- bf16 TN GEMM
// C[m][n] = sum_k A[m][k]*Bm[n][k].  All-bf16, all-gload16 staging.
// Depth-2 prefetch (T3/T4): triple-buffered LDS; stage(t+2) issued at iter t;
// counted-vmcnt barrier drains only tile t+1, keeps tile t+2 in flight.
//   MODE 0: store fp32 split-K partial at z*MN
//   MODE 1: direct bf16 store of acc+bias (ACT=1: exact gelu) -> C is bf16*
//   MODE 2: fused loss sum((C+bias-x0)^2) * 1/(B*N), one atomic per block
//           directly into the output scalar (zeroed by k_prep)
template <int BM, int BN, int MODE, int ACT = 0>
__global__ __launch_bounds__(256) void gemm_tn(
    const bf16* __restrict__ A, const bf16* __restrict__ Bm,
    float* __restrict__ C, int N, int K, int kLen, int MN,
    const float* __restrict__ bias, const float* __restrict__ x0,
    float* __restrict__ lossOut) {
  constexpr int WM = BM / 2, WN = BN / 2, FM = WM / 16, FN = WN / 16;
  constexpr int PASS = (BM + BN) / 64;  // 64B-chunk groups per stage (per wave)
  constexpr int KEEP = PASS;
  __shared__ __align__(16) bf16 As[3][BM * 32];
  __shared__ __align__(16) bf16 Bs[3][BN * 32];
  __shared__ float lred[4];
  const int tid = threadIdx.x;
  const int lane = tid & 63, w = tid >> 6;
  const int wm = w >> 1, wn = w & 1;
  const int mBase = blockIdx.x * BM, nBase = blockIdx.y * BN;
  const int k0 = blockIdx.z * kLen;
  const int nIter = kLen >> 5;            // even (16) at every call site

  f32x4 acc[FM][FN];
#pragma unroll
  for (int i = 0; i < FM; i++)
#pragma unroll
    for (int j = 0; j < FN; j++) acc[i][j] = {0.f, 0.f, 0.f, 0.f};

  // stage: chunk u (16B) covers (row = u>>2, sub = u&3) of the 32-wide K-slice.
  // Chunks c < BM/16 load A, the rest load B.  LDS dest is wave-uniform.
  auto stage = [&](int buf, int k) {
#pragma unroll
    for (int p = 0; p < PASS; p++) {
      int c = p * 4 + w;
      int u = c * 64 + lane;
      if (c < BM / 16) {
        int row = u >> 2, sub = u & 3;
        gload16(A + (size_t)(mBase + row) * K + k + sub * 8,
                (char*)As[buf] + c * 1024);
      } else {
        int u2 = u - BM * 4;
        int row = u2 >> 2, sub = u2 & 3;
        gload16(Bm + (size_t)(nBase + row) * K + k + sub * 8,
                (char*)Bs[buf] + (c - BM / 16) * 1024);
      }
    }
  };
  auto compute = [&](int cur) {
    bf16x8 af[FM], bfr[FN];
#pragma unroll
    for (int i = 0; i < FM; i++)
      af[i] = *(const bf16x8*)(As[cur] + (wm * WM + i * 16 + (lane & 15)) * 32 + (lane >> 4) * 8);
#pragma unroll
    for (int j = 0; j < FN; j++)
      bfr[j] = *(const bf16x8*)(Bs[cur] + (wn * WN + j * 16 + (lane & 15)) * 32 + (lane >> 4) * 8);
#pragma unroll
    for (int i = 0; i < FM; i++)
#pragma unroll
      for (int j = 0; j < FN; j++)
        acc[i][j] = __builtin_amdgcn_mfma_f32_16x16x32_bf16(af[i], bfr[j], acc[i][j], 0, 0, 0);
  };

  // prologue: stage tiles 0 and 1; keep tile 1 in flight across the barrier.
  stage(0, k0);
  if (nIter > 1) {
    stage(1, k0 + 32);
    bar_keep<KEEP>();
  } else {
    bar_keep<0>();
  }

  // main loop, pair-unrolled; LDS buffers rotate mod 3.
  int c0 = 0, c1 = 1, c2 = 2;
  for (int t = 0; t < nIter; t += 2) {
    {
      const bool more2 = (t + 2 < nIter);
      if (more2) stage(c2, k0 + (t + 2) * 32);
      compute(c0);
      if (more2) bar_keep<KEEP>(); else bar_keep<0>();
    }
    {
      const bool more3 = (t + 3 < nIter);
      if (more3) stage(c0, k0 + (t + 3) * 32);
      compute(c1);
      if (more3) bar_keep<KEEP>(); else bar_keep<0>();
    }
    int tmp = c2; c2 = c1; c1 = c0; c0 = tmp;
  }

  if constexpr (MODE == 0) {
    float* Cz = C + (size_t)blockIdx.z * MN;
#pragma unroll
    for (int i = 0; i < FM; i++)
#pragma unroll
      for (int j = 0; j < FN; j++) {
        int n  = nBase + wn * WN + j * 16 + (lane & 15);
        int mB = mBase + wm * WM + i * 16 + ((lane >> 4) << 2);
#pragma unroll
        for (int r = 0; r < 4; r++)
          Cz[(size_t)(mB + r) * N + n] = acc[i][j][r];
      }
  } else if constexpr (MODE == 1) {
    bf16* Cb = (bf16*)C;
#pragma unroll
    for (int i = 0; i < FM; i++)
#pragma unroll
      for (int j = 0; j < FN; j++) {
        int n  = nBase + wn * WN + j * 16 + (lane & 15);
        float bo = bias[n];
        int mB = mBase + wm * WM + i * 16 + ((lane >> 4) << 2);
#pragma unroll
        for (int r = 0; r < 4; r++) {
          float x = acc[i][j][r] + bo;
          if constexpr (ACT == 1)
            x = 0.5f * x * (1.f + erff(x * 0.70710678118654752f));
          Cb[(size_t)(mB + r) * N + n] = (bf16)x;
        }
      }
  } else {
    float lsum = 0.f;
#pragma unroll
    for (int i = 0; i < FM; i++)
#pragma unroll
      for (int j = 0; j < FN; j++) {
        int n  = nBase + wn * WN + j * 16 + (lane & 15);
        float bo = bias[n];
        int mB = mBase + wm * WM + i * 16 + ((lane >> 4) << 2);
#pragma unroll
        for (int r = 0; r < 4; r++) {
          float d = acc[i][j][r] + bo - x0[(size_t)(mB + r) * N + n];
          lsum += d * d;
        }
      }
    for (int off = 32; off > 0; off >>= 1) lsum += __shfl_down(lsum, off, 64);
    if (lane == 0) lred[w] = lsum;
    __syncthreads();
    if (tid == 0)
      atomicAdd(lossOut,
                (lred[0] + lred[1] + lred[2] + lred[3]) * (1.f / 4194304.f));
  }
}

// ------------- h = sum_32 partials + b_in + time-embed; write fp32 + bf16
__global__ __launch_bounds__(512) void k_epi_h(const float* __restrict__ P,
                                               const float* __restrict__ t,
                                               const float* __restrict__ W_t1,
                                               const float* __restrict__ b_t1,
                                               const float* __restrict__ W_t2,
                                               const float* __restrict__ b_t2,
                                               const float* __restrict__ b_in,
                                               float* __restrict__ h_f32,
                                               bf16* __restrict__ h_b) {
  int b = blockIdx.x, d = threadIdx.x;
  __shared__ float s[32];
  if (d < 32) {
    float z = t[b] * W_t1[d] + b_t1[d];   // t_norm == t
    s[d] = z / (1.f + expf(-z));          // silu
  }
  __syncthreads();
  int i = b * Dd + d;
  float v = b_in[d] + b_t2[d];
#pragma unroll
  for (int sp = 0; sp < 32; sp++) v += P[sp * (Bb * Dd) + i];
#pragma unroll
  for (int j = 0; j < 32; j++) v += s[j] * W_t2[d * 32 + j];
  h_f32[i] = v;
  h_b[i] = (bf16)v;
}

// -------- LayerNorm over D=512: x = base + sum_NS add + bias; y = LN(x)*g+be
template <int NS>
__global__ __launch_bounds__(512) void k_ln(const float* __restrict__ base,
                                            const float* __restrict__ add,
                                            const float* __restrict__ bias,
                                            const float* __restrict__ g,
                                            const float* __restrict__ be,
                                            float* __restrict__ out_f32,
                                            bf16* __restrict__ out_b) {
  int b = blockIdx.x, d = threadIdx.x;
  __shared__ float red[16];
  int i = b * Dd + d;
  float x = base[i] + bias[d];
#pragma unroll
  for (int sp = 0; sp < NS; sp++) x += add[sp * (Bb * Dd) + i];
  int w = d >> 6, lane = d & 63;
  float s = x;
  for (int off = 32; off > 0; off >>= 1) s += __shfl_down(s, off, 64);
  if (lane == 0) red[w] = s;
  __syncthreads();
  if (d == 0) {
    float tot = 0.f;
    for (int q = 0; q < 8; q++) tot += red[q];
    red[8] = tot * (1.f / 512.f);
  }
  __syncthreads();
  float mu = red[8];
  float c = x - mu;
  float s2 = c * c;
  for (int off = 32; off > 0; off >>= 1) s2 += __shfl_down(s2, off, 64);
  if (lane == 0) red[w] = s2;
  __syncthreads();
  if (d == 0) {
    float tot = 0.f;
    for (int q = 0; q < 8; q++) tot += red[q];
    red[8] = tot * (1.f / 512.f);
  }
  __syncthreads();
  float var = red[8];
  float y = c * rsqrtf(var + 1e-5f) * g[d] + be[d];
  if (out_f32) out_f32[i] = y;
  out_b[i] = (bf16)y;
}

// ======================================================================= host
extern "C" void kernel_launch(void* const* d_in, const int* in_sizes, int n_in,
                              void* d_out, int out_size, void* d_ws, size_t ws_size,
                              hipStream_t stream) {
  const float* x0    = (const float*)d_in[0];
  const float* t     = (const float*)d_in[1];
  const float* Lv    = (const float*)d_in[2];
  const float* W_in  = (const float*)d_in[3];
  const float* b_in  = (const float*)d_in[4];
  const float* W_out = (const float*)d_in[5];
  const float* b_out = (const float*)d_in[6];
  const float* W_qkv = (const float*)d_in[7];
  const float* b_qkv = (const float*)d_in[8];
  const float* W_o   = (const float*)d_in[9];
  const float* b_o   = (const float*)d_in[10];
  const float* g1    = (const float*)d_in[11];
  const float* be1   = (const float*)d_in[12];
  const float* g2    = (const float*)d_in[13];
  const float* be2   = (const float*)d_in[14];
  const float* W_f1  = (const float*)d_in[15];
  const float* b_f1  = (const float*)d_in[16];
  const float* W_f2  = (const float*)d_in[17];
  const float* b_f2  = (const float*)d_in[18];
  const float* W_t1  = (const float*)d_in[19];
  const float* b_t1  = (const float*)d_in[20];
  const float* W_t2  = (const float*)d_in[21];
  const float* b_t2  = (const float*)d_in[22];
  const int* L_rows  = (const int*)d_in[23];
  const int* L_cols  = (const int*)d_in[24];

  size_t off = 0;
  char* ws = (char*)d_ws;
  auto carve = [&](size_t bytes) -> void* {
    void* p = ws + off;
    off += (bytes + 255) & ~(size_t)255;
    return p;
  };

  bf16* W_v_b    = (bf16*)carve((size_t)Dd * Dd * 2);
  bf16* W_o_b    = (bf16*)carve((size_t)Dd * Dd * 2);
  bf16* W_f1_b   = (bf16*)carve((size_t)DFf * Dd * 2);
  bf16* W_f2_b   = (bf16*)carve((size_t)Dd * DFf * 2);
  bf16* W_in_b   = (bf16*)carve((size_t)Dd * Nn * 2);        // 16.8 MB
  bf16* W_out_b  = (bf16*)carve((size_t)Nn * Dd * 2);        // 16.8 MB
  bf16* x0T_b    = (bf16*)carve((size_t)Nn * Bb * 2);
  unsigned char* x0F_b = (unsigned char*)carve((size_t)Nn * Bb);  // 4.2 MB fp8
  bf16* Lx_b     = (bf16*)carve((size_t)Nn * Bb * 2);
  bf16* xt_b     = (bf16*)carve((size_t)Bb * Nn * 2);
  float* p_h     = (float*)carve((size_t)32 * Bb * Dd * 4);  // 16 MB
  float* p_at    = (float*)carve((size_t)Bb * Dd * 4);
  float* p_f2    = (float*)carve((size_t)4 * Bb * Dd * 4);
  float* h_f32   = (float*)carve((size_t)Bb * Dd * 4);
  bf16* h_b      = (bf16*)carve((size_t)Bb * Dd * 2);
  bf16* v_b      = (bf16*)carve((size_t)Bb * Dd * 2);
  float* hln_f32 = (float*)carve((size_t)Bb * Dd * 4);
  bf16* hln_b    = (bf16*)carve((size_t)Bb * Dd * 2);
  bf16* f1_b     = (bf16*)carve((size_t)Bb * DFf * 2);
  bf16* h2_b     = (bf16*)carve((size_t)Bb * Dd * 2);
  int* counts    = (int*)carve((size_t)Nn * 4);
  unsigned* ents = (unsigned*)carve((size_t)Nn * SLOT * 4);  // 4.2 MB
  (void)in_sizes; (void)n_in; (void)out_size; (void)ws_size; (void)Lv;

  hipMemsetAsync(counts, 0, (size_t)Nn * 4, stream);

  // prep: weight cvt (x6) | x0 transpose (bf16 + fp8) | nnz bucketing;
  // also zeroes the output loss scalar.
  k_prep<<<PREP_BLKS, 256, 0, stream>>>(
      W_qkv + (size_t)2 * Dd * Dd, W_o, W_f1, W_f2, W_in, W_out,
      W_v_b, W_o_b, W_f1_b, W_f2_b, W_in_b, W_out_b,
      x0, x0T_b, x0F_b, L_rows, L_cols, Lv, counts, ents, (float*)d_out);

  // Lx gather from the fp8 table (half the L3 gather bytes)
  k_lx<<<Nn / 4, 256, 0, stream>>>((const unsigned*)x0F_b, counts, ents,
                                   (bf16x4*)Lx_b);
  // x_t from bf16 [n][b] buffers (x0T + Lx)
  k_combine<<<dim3(256, 4), 256, 0, stream>>>(x0T_b, Lx_b, t, xt_b);

  // h = x_t @ W_in^T   (M=256,N=512,K=16384, split-K=32; BM=128 halves B re-reads)
  gemm_tn<128, 64, 0><<<dim3(2, 8, 32), 256, 0, stream>>>(
      xt_b, W_in_b, p_h, Dd, Nn, 512, Bb * Dd, nullptr, nullptr, nullptr);
  k_epi_h<<<Bb, 512, 0, stream>>>(p_h, t, W_t1, b_t1, W_t2, b_t2, b_in, h_f32, h_b);

  // v = h @ W_qkv_v^T + bias  (32x32 tiles -> 128 blocks)
  gemm_tn<32, 32, 1><<<dim3(8, 16, 1), 256, 0, stream>>>(
      h_b, W_v_b, (float*)v_b, Dd, Dd, 512, 0, b_qkv + 2 * Dd, nullptr, nullptr);

  // attn_out = v @ W_o^T  (bias folded into LN; 128 blocks)
  gemm_tn<32, 32, 0><<<dim3(8, 16, 1), 256, 0, stream>>>(
      v_b, W_o_b, p_at, Dd, Dd, 512, 0, nullptr, nullptr, nullptr);
  k_ln<1><<<Bb, 512, 0, stream>>>(h_f32, p_at, b_o, g1, be1, hln_f32, hln_b);

  // ff1 = gelu(hln @ W_f1^T + b_f1)  (32x32 tiles -> 512 blocks)
  gemm_tn<32, 32, 1, 1><<<dim3(8, 64, 1), 256, 0, stream>>>(
      hln_b, W_f1_b, (float*)f1_b, DFf, Dd, 512, 0, b_f1, nullptr, nullptr);

  // ff2 = ff1 @ W_f2^T  (K=2048, split-K=4, 32x32 tiles -> 512 blocks)
  gemm_tn<32, 32, 0><<<dim3(8, 16, 4), 256, 0, stream>>>(
      f1_b, W_f2_b, p_f2, Dd, DFf, 512, Bb * Dd, nullptr, nullptr, nullptr);
  k_ln<4><<<Bb, 512, 0, stream>>>(hln_f32, p_f2, b_f2, g2, be2, nullptr, h2_b);

  // pred = h2 @ W_out^T + b_out, fused+scaled loss straight into d_out
  gemm_tn<128, 64, 2><<<dim3(2, 256, 1), 256, 0, stream>>>(
      h2_b, W_out_b, nullptr, Nn, Dd, 512, 0, b_out, x0, (float*)d_out);
}